// Round 1
// baseline (2092.705 us; speedup 1.0000x reference)
//
#include <hip/hip_runtime.h>
#include <hip/hip_bf16.h>
#include <math.h>

#define HW 102400        // 320*320
#define NPIX 102400
#define KSEL 4096
#define CAP 16384

// ---------- helpers ----------
__device__ inline unsigned fkey(float f) {
    unsigned u = __float_as_uint(f);
    return (u & 0x80000000u) ? ~u : (u | 0x80000000u);
}

// wave64 sum reduction via DPP (row_shr 1/2/4/8, row_bcast 15/31), result broadcast
__device__ inline unsigned wave_sum64(unsigned x) {
    x += (unsigned)__builtin_amdgcn_update_dpp(0, (int)x, 0x111, 0xf, 0xf, false);
    x += (unsigned)__builtin_amdgcn_update_dpp(0, (int)x, 0x112, 0xf, 0xf, false);
    x += (unsigned)__builtin_amdgcn_update_dpp(0, (int)x, 0x114, 0xf, 0xf, false);
    x += (unsigned)__builtin_amdgcn_update_dpp(0, (int)x, 0x118, 0xf, 0xf, false);
    x += (unsigned)__builtin_amdgcn_update_dpp(0, (int)x, 0x142, 0xa, 0xf, false);
    x += (unsigned)__builtin_amdgcn_update_dpp(0, (int)x, 0x143, 0xc, 0xf, false);
    return (unsigned)__shfl((int)x, 63);
}

// ---------- K1: score + class argmax ----------
__global__ __launch_bounds__(256) void k_score(const float* __restrict__ x,
                                               const float* __restrict__ sm,
                                               float* __restrict__ score,
                                               int* __restrict__ clsidx) {
    __shared__ float smt[256][16];   // smt[c][k] = sm[k*256+c]
    int t = threadIdx.x;
    for (int i = t; i < 4096; i += 256) {
        int k = i >> 8, c = i & 255;
        smt[c][k] = sm[k * 256 + c];
    }
    __syncthreads();
    int n = blockIdx.x * 256 + t;
    float acc[16];
#pragma unroll
    for (int k = 0; k < 16; ++k) acc[k] = 0.f;
    const float* xp = x + (size_t)5 * HW + n;
#pragma unroll 4
    for (int c = 0; c < 256; ++c) {
        float xv = xp[(size_t)c * HW];
        const float4* s4 = reinterpret_cast<const float4*>(smt[c]);
        float4 a = s4[0], b = s4[1], cc = s4[2], d = s4[3];
        acc[0]  = fmaf(xv, a.x,  acc[0]);  acc[1]  = fmaf(xv, a.y,  acc[1]);
        acc[2]  = fmaf(xv, a.z,  acc[2]);  acc[3]  = fmaf(xv, a.w,  acc[3]);
        acc[4]  = fmaf(xv, b.x,  acc[4]);  acc[5]  = fmaf(xv, b.y,  acc[5]);
        acc[6]  = fmaf(xv, b.z,  acc[6]);  acc[7]  = fmaf(xv, b.w,  acc[7]);
        acc[8]  = fmaf(xv, cc.x, acc[8]);  acc[9]  = fmaf(xv, cc.y, acc[9]);
        acc[10] = fmaf(xv, cc.z, acc[10]); acc[11] = fmaf(xv, cc.w, acc[11]);
        acc[12] = fmaf(xv, d.x,  acc[12]); acc[13] = fmaf(xv, d.y,  acc[13]);
        acc[14] = fmaf(xv, d.z,  acc[14]); acc[15] = fmaf(xv, d.w,  acc[15]);
    }
    float mv = acc[0]; int mi = 0;
#pragma unroll
    for (int k = 1; k < 16; ++k) { if (acc[k] > mv) { mv = acc[k]; mi = k; } }
    float x0 = x[n];
    float sig = 1.0f / (1.0f + expf(-x0));
    float sc = (sig > 0.5f) ? sig * mv : -INFINITY;
    score[n] = sc;
    clsidx[n] = mi;
}

// ---------- K2: 16-bit-prefix histogram ----------
__global__ void k_hist(const float* __restrict__ score, unsigned* __restrict__ hist) {
    int n = blockIdx.x * 256 + threadIdx.x;
    unsigned key = fkey(score[n]);
    atomicAdd(&hist[key >> 16], 1u);
}

// ---------- K3: find 16-bit prefix p16 such that count(key>>16 >= p16) >= K ----------
__global__ __launch_bounds__(1024) void k_findp(const unsigned* __restrict__ hist,
                                                unsigned* __restrict__ meta) {
    __shared__ unsigned part[1024];
    __shared__ unsigned sgrp, s_after;
    __shared__ unsigned bins[64];
    int t = threadIdx.x;
    if (t == 0) { sgrp = 0; s_after = 0; }
    unsigned s = 0;
    const unsigned* hp = hist + t * 64;
    for (int i = 0; i < 64; ++i) s += hp[i];
    part[t] = s;
    __syncthreads();
    for (int off = 1; off < 1024; off <<= 1) {
        unsigned v = (t + off < 1024) ? part[t + off] : 0u;
        __syncthreads();
        part[t] += v;
        __syncthreads();
    }
    if (part[t] >= KSEL && (t == 1023 || part[t + 1] < KSEL)) {
        sgrp = (unsigned)t;
        s_after = (t == 1023) ? 0u : part[t + 1];
    }
    __syncthreads();
    unsigned g = sgrp, SA = s_after;
    if (t < 64) bins[t] = hist[g * 64 + t];
    __syncthreads();
    if (t == 0) {
        unsigned acc = SA, p = g * 64;
        for (int b = 63; b >= 0; --b) {
            acc += bins[b];
            if (acc >= KSEL) { p = g * 64 + (unsigned)b; break; }
        }
        meta[1] = p;
    }
}

// ---------- K4: collect candidates with key>>16 >= p16 ----------
__global__ void k_collect(const float* __restrict__ score,
                          unsigned* __restrict__ meta,
                          unsigned long long* __restrict__ cand) {
    int n = blockIdx.x * 256 + threadIdx.x;
    unsigned key = fkey(score[n]);
    if ((key >> 16) >= meta[1]) {
        unsigned pos = atomicAdd(&meta[0], 1u);
        if (pos < CAP)
            cand[pos] = ((unsigned long long)key << 32) | (unsigned)(~(unsigned)n);
    }
}

// ---------- K5: rank candidates (exact top-k ordering) + gather ----------
__global__ __launch_bounds__(256) void k_rank(const unsigned long long* __restrict__ cand,
                                              const unsigned* __restrict__ meta,
                                              const float* __restrict__ x,
                                              const float* __restrict__ score,
                                              const int* __restrict__ clsidx,
                                              float* __restrict__ topv,
                                              float* __restrict__ bl, float* __restrict__ bt,
                                              float* __restrict__ br, float* __restrict__ bb,
                                              float* __restrict__ area, int* __restrict__ clsk) {
    __shared__ unsigned long long tile[1024];
    int C = (int)meta[0]; if (C > CAP) C = CAP;
    int j = blockIdx.x * 256 + threadIdx.x;
    unsigned long long kj = (j < C) ? cand[j] : 0ull;
    unsigned rank = 0;
    for (int tb = 0; tb < C; tb += 1024) {
        int cnt = min(1024, C - tb);
        __syncthreads();
        for (int u = threadIdx.x; u < cnt; u += 256) tile[u] = cand[tb + u];
        __syncthreads();
        if (j < C)
            for (int u = 0; u < cnt; ++u) rank += (tile[u] > kj) ? 1u : 0u;
    }
    if (j < C && rank < KSEL) {
        unsigned n = ~(unsigned)(kj & 0xFFFFFFFFull);
        float l  = x[(size_t)1 * HW + n];
        float tt = x[(size_t)2 * HW + n];
        float r  = x[(size_t)3 * HW + n];
        float b  = x[(size_t)4 * HW + n];
        topv[rank] = score[n];
        bl[rank] = l; bt[rank] = tt; br[rank] = r; bb[rank] = b;
        area[rank] = (r - l) * (b - tt);
        clsk[rank] = clsidx[n];
    }
}

// ---------- K6: pairwise IoU >= 0.2 bitmask (4096 rows x 64 u64 words) ----------
__global__ __launch_bounds__(256) void k_mask(const float* __restrict__ bl, const float* __restrict__ bt,
                                              const float* __restrict__ br, const float* __restrict__ bb,
                                              const float* __restrict__ area,
                                              unsigned long long* __restrict__ mask) {
    int tid = blockIdx.x * 256 + threadIdx.x;
    int i = tid >> 6, w = tid & 63;
    float li = bl[i], ti = bt[i], ri = br[i], bi = bb[i], ai = area[i];
    unsigned long long m = 0;
    int j0 = w * 64;
    for (int k = 0; k < 64; ++k) {
        int j = j0 + k;
        float iw = fminf(ri, br[j]) - fmaxf(li, bl[j]); iw = fmaxf(iw, 0.f);
        float ih = fminf(bi, bb[j]) - fmaxf(ti, bt[j]); ih = fmaxf(ih, 0.f);
        float inter = iw * ih;
        float uni = ai + area[j] - inter + 1e-10f;
        float iou = inter / uni;
        if (iou >= 0.2f) m |= (1ull << k);
    }
    mask[(size_t)i * 64 + w] = m;
}

// ---------- K7: sequential greedy scan, 1 wave ----------
__global__ __launch_bounds__(64) void k_nms(const unsigned long long* __restrict__ mask,
                                            const float* __restrict__ topv,
                                            const float* __restrict__ area,
                                            unsigned long long* __restrict__ keptW) {
    int lane = threadIdx.x;
    unsigned long long alive = 0;
    const float* tp = topv + lane * 64;
    for (int k = 0; k < 64; ++k)
        if (tp[k] != -INFINITY) alive |= (1ull << k);
    unsigned long long kept = 0;
    for (;;) {
        unsigned long long nz = __ballot(alive != 0ull);
        if (!nz) break;
        int w0 = __ffsll((unsigned long long)nz) - 1;
        unsigned long long word = __shfl(alive, w0);
        int b0 = __ffsll(word) - 1;
        int i = w0 * 64 + b0;
        if (lane == w0) alive &= ~(1ull << b0);            // clear alive[i] first
        unsigned long long m = mask[(size_t)i * 64 + lane];
        unsigned c = (unsigned)__popcll(m & alive);
        unsigned tot = wave_sum64(c);
        float ai = area[i];
        bool accept = (ai >= 4.0f) && (tot >= 10u);
        if (accept) {
            alive &= ~m;                                    // suppress overlaps
            if (lane == w0) kept |= (1ull << b0);
        }
    }
    keptW[lane] = kept;
}

// ---------- K8: epilogue ----------
__global__ __launch_bounds__(256) void k_out(const unsigned long long* __restrict__ keptW,
                                             const float* __restrict__ topv,
                                             const float* __restrict__ bl, const float* __restrict__ bt,
                                             const float* __restrict__ br, const float* __restrict__ bb,
                                             const int* __restrict__ clsk,
                                             const float* __restrict__ padding,
                                             const float* __restrict__ ratio,
                                             const int* __restrict__ piw, const int* __restrict__ pih,
                                             float* __restrict__ out) {
    int i = blockIdx.x * 256 + threadIdx.x;
    if (i >= KSEL) return;
    bool kept = (keptW[i >> 6] >> (i & 63)) & 1ull;
    float tv = topv[i];
    bool keep = kept && (tv >= 0.5f);
    float p0 = padding[0], p1 = padding[1];
    float invr = 1.0f / ratio[0];
    float W_ = (float)piw[0], H_ = (float)pih[0];
    float x1 = fmaxf((bl[i] - p0) * invr, 0.f);
    float y1 = fmaxf((bt[i] - p1) * invr, 0.f);
    float x2 = fminf((br[i] - p0) * invr, W_);
    float y2 = fminf((bb[i] - p1) * invr, H_);
    keep = keep && (x1 < W_) && (y1 < H_);
    float* o = out + (size_t)i * 7;
    if (keep) {
        o[0] = 1.0f; o[1] = tv; o[2] = x1; o[3] = y1; o[4] = x2; o[5] = y2;
        o[6] = (float)clsk[i];
    } else {
        o[0] = 0.f; o[1] = 0.f; o[2] = 0.f; o[3] = 0.f; o[4] = 0.f; o[5] = 0.f; o[6] = 0.f;
    }
}

extern "C" void kernel_launch(void* const* d_in, const int* in_sizes, int n_in,
                              void* d_out, int out_size, void* d_ws, size_t ws_size,
                              hipStream_t stream) {
    const float* x       = (const float*)d_in[0];
    const float* sm      = (const float*)d_in[1];
    const float* padding = (const float*)d_in[2];
    const float* ratio   = (const float*)d_in[3];
    const int*   piw     = (const int*)d_in[4];
    const int*   pih     = (const int*)d_in[5];
    float* out = (float*)d_out;
    char* ws = (char*)d_ws;

    // workspace layout (bytes)
    float* score               = (float*)(ws + 0);                 // 409600
    int*   clsidx              = (int*)(ws + 409600);              // 409600
    unsigned* hist             = (unsigned*)(ws + 819200);         // 262144
    unsigned* meta             = (unsigned*)(ws + 1081344);        // 512 (meta[0]=counter, meta[1]=p16)
    unsigned long long* cand   = (unsigned long long*)(ws + 1081856); // CAP*8 = 131072
    float* topv                = (float*)(ws + 1212928);           // 16384
    float* bl                  = (float*)(ws + 1229312);
    float* bt                  = (float*)(ws + 1245696);
    float* br                  = (float*)(ws + 1262080);
    float* bb                  = (float*)(ws + 1278464);
    float* area                = (float*)(ws + 1294848);
    int*   clsk                = (int*)(ws + 1311232);
    unsigned long long* keptW  = (unsigned long long*)(ws + 1327616); // 512
    unsigned long long* mask   = (unsigned long long*)(ws + 1328128); // 2097152

    hipMemsetAsync(hist, 0, 262144 + 512, stream);  // hist + meta

    k_score  <<<400, 256, 0, stream>>>(x, sm, score, clsidx);
    k_hist   <<<400, 256, 0, stream>>>(score, hist);
    k_findp  <<<1, 1024, 0, stream>>>(hist, meta);
    k_collect<<<400, 256, 0, stream>>>(score, meta, cand);
    k_rank   <<<CAP / 256, 256, 0, stream>>>(cand, meta, x, score, clsidx,
                                             topv, bl, bt, br, bb, area, clsk);
    k_mask   <<<1024, 256, 0, stream>>>(bl, bt, br, bb, area, mask);
    k_nms    <<<1, 64, 0, stream>>>(mask, topv, area, keptW);
    k_out    <<<16, 256, 0, stream>>>(keptW, topv, bl, bt, br, bb, clsk,
                                      padding, ratio, piw, pih, out);
}

// Round 2
// 1265.818 us; speedup vs baseline: 1.6532x; 1.6532x over previous
//
#include <hip/hip_runtime.h>
#include <hip/hip_bf16.h>
#include <math.h>

#define HW 102400        // 320*320
#define KSEL 4096
#define CAP 16384

// ---------- helpers ----------
__device__ inline unsigned fkey(float f) {
    unsigned u = __float_as_uint(f);
    return (u & 0x80000000u) ? ~u : (u | 0x80000000u);
}

// wave64 sum reduction via DPP (row_shr 1/2/4/8, row_bcast 15/31), result broadcast
__device__ inline unsigned wave_sum64(unsigned x) {
    x += (unsigned)__builtin_amdgcn_update_dpp(0, (int)x, 0x111, 0xf, 0xf, false);
    x += (unsigned)__builtin_amdgcn_update_dpp(0, (int)x, 0x112, 0xf, 0xf, false);
    x += (unsigned)__builtin_amdgcn_update_dpp(0, (int)x, 0x114, 0xf, 0xf, false);
    x += (unsigned)__builtin_amdgcn_update_dpp(0, (int)x, 0x118, 0xf, 0xf, false);
    x += (unsigned)__builtin_amdgcn_update_dpp(0, (int)x, 0x142, 0xa, 0xf, false);
    x += (unsigned)__builtin_amdgcn_update_dpp(0, (int)x, 0x143, 0xc, 0xf, false);
    return (unsigned)__shfl((int)x, 63);
}

// ---------- K1: score + class argmax (+ fused histogram) ----------
__global__ __launch_bounds__(256) void k_score(const float* __restrict__ x,
                                               const float* __restrict__ sm,
                                               float* __restrict__ score,
                                               int* __restrict__ clsidx,
                                               unsigned* __restrict__ hist) {
    __shared__ float smt[256][16];   // smt[c][k] = sm[k*256+c]
    int t = threadIdx.x;
    for (int i = t; i < 4096; i += 256) {
        int k = i >> 8, c = i & 255;
        smt[c][k] = sm[k * 256 + c];
    }
    __syncthreads();
    int n = blockIdx.x * 256 + t;
    float acc[16];
#pragma unroll
    for (int k = 0; k < 16; ++k) acc[k] = 0.f;
    const float* xp = x + (size_t)5 * HW + n;
#pragma unroll 4
    for (int c = 0; c < 256; ++c) {
        float xv = xp[(size_t)c * HW];
        const float4* s4 = reinterpret_cast<const float4*>(smt[c]);
        float4 a = s4[0], b = s4[1], cc = s4[2], d = s4[3];
        acc[0]  = fmaf(xv, a.x,  acc[0]);  acc[1]  = fmaf(xv, a.y,  acc[1]);
        acc[2]  = fmaf(xv, a.z,  acc[2]);  acc[3]  = fmaf(xv, a.w,  acc[3]);
        acc[4]  = fmaf(xv, b.x,  acc[4]);  acc[5]  = fmaf(xv, b.y,  acc[5]);
        acc[6]  = fmaf(xv, b.z,  acc[6]);  acc[7]  = fmaf(xv, b.w,  acc[7]);
        acc[8]  = fmaf(xv, cc.x, acc[8]);  acc[9]  = fmaf(xv, cc.y, acc[9]);
        acc[10] = fmaf(xv, cc.z, acc[10]); acc[11] = fmaf(xv, cc.w, acc[11]);
        acc[12] = fmaf(xv, d.x,  acc[12]); acc[13] = fmaf(xv, d.y,  acc[13]);
        acc[14] = fmaf(xv, d.z,  acc[14]); acc[15] = fmaf(xv, d.w,  acc[15]);
    }
    float mv = acc[0]; int mi = 0;
#pragma unroll
    for (int k = 1; k < 16; ++k) { if (acc[k] > mv) { mv = acc[k]; mi = k; } }
    float x0 = x[n];
    float sig = 1.0f / (1.0f + expf(-x0));
    float sc = (sig > 0.5f) ? sig * mv : -INFINITY;
    score[n] = sc;
    clsidx[n] = mi;
    atomicAdd(&hist[fkey(sc) >> 16], 1u);
}

// ---------- K3: find 16-bit prefix p16 such that count(key>>16 >= p16) >= K ----------
__global__ __launch_bounds__(1024) void k_findp(const unsigned* __restrict__ hist,
                                                unsigned* __restrict__ meta) {
    __shared__ unsigned part[1024];
    __shared__ unsigned sgrp, s_after;
    __shared__ unsigned bins[64];
    int t = threadIdx.x;
    if (t == 0) { sgrp = 0; s_after = 0; }
    unsigned s = 0;
    const unsigned* hp = hist + t * 64;
    for (int i = 0; i < 64; ++i) s += hp[i];
    part[t] = s;
    __syncthreads();
    for (int off = 1; off < 1024; off <<= 1) {
        unsigned v = (t + off < 1024) ? part[t + off] : 0u;
        __syncthreads();
        part[t] += v;
        __syncthreads();
    }
    if (part[t] >= KSEL && (t == 1023 || part[t + 1] < KSEL)) {
        sgrp = (unsigned)t;
        s_after = (t == 1023) ? 0u : part[t + 1];
    }
    __syncthreads();
    unsigned g = sgrp, SA = s_after;
    if (t < 64) bins[t] = hist[g * 64 + t];
    __syncthreads();
    if (t == 0) {
        unsigned acc = SA, p = g * 64;
        for (int b = 63; b >= 0; --b) {
            acc += bins[b];
            if (acc >= KSEL) { p = g * 64 + (unsigned)b; break; }
        }
        meta[1] = p;
    }
}

// ---------- K4: collect candidates with key>>16 >= p16 ----------
__global__ void k_collect(const float* __restrict__ score,
                          unsigned* __restrict__ meta,
                          unsigned long long* __restrict__ cand) {
    int n = blockIdx.x * 256 + threadIdx.x;
    unsigned key = fkey(score[n]);
    if ((key >> 16) >= meta[1]) {
        unsigned pos = atomicAdd(&meta[0], 1u);
        if (pos < CAP)
            cand[pos] = ((unsigned long long)key << 32) | (unsigned)(~(unsigned)n);
    }
}

// ---------- K5: rank candidates (exact top-k ordering) + gather ----------
__global__ __launch_bounds__(256) void k_rank(const unsigned long long* __restrict__ cand,
                                              const unsigned* __restrict__ meta,
                                              const float* __restrict__ x,
                                              const float* __restrict__ score,
                                              const int* __restrict__ clsidx,
                                              float* __restrict__ topv,
                                              float* __restrict__ bl, float* __restrict__ bt,
                                              float* __restrict__ br, float* __restrict__ bb,
                                              float* __restrict__ area, int* __restrict__ clsk) {
    __shared__ unsigned long long tile[1024];
    int C = (int)meta[0]; if (C > CAP) C = CAP;
    int j = blockIdx.x * 256 + threadIdx.x;
    unsigned long long kj = (j < C) ? cand[j] : 0ull;
    unsigned rank = 0;
    for (int tb = 0; tb < C; tb += 1024) {
        int cnt = min(1024, C - tb);
        __syncthreads();
        for (int u = threadIdx.x; u < cnt; u += 256) tile[u] = cand[tb + u];
        __syncthreads();
        if (j < C)
            for (int u = 0; u < cnt; ++u) rank += (tile[u] > kj) ? 1u : 0u;
    }
    if (j < C && rank < KSEL) {
        unsigned n = ~(unsigned)(kj & 0xFFFFFFFFull);
        float l  = x[(size_t)1 * HW + n];
        float tt = x[(size_t)2 * HW + n];
        float r  = x[(size_t)3 * HW + n];
        float b  = x[(size_t)4 * HW + n];
        topv[rank] = score[n];
        bl[rank] = l; bt[rank] = tt; br[rank] = r; bb[rank] = b;
        area[rank] = (r - l) * (b - tt);
        clsk[rank] = clsidx[n];
    }
}

// ---------- K6: pairwise IoU >= 0.2 bitmask, TRANSPOSED layout mask2[w][i] ----------
// grid: 256 blocks = 16 i-chunks x 16 j-chunks; LDS-staged j-slice, broadcast reads.
__global__ __launch_bounds__(256) void k_mask(const float* __restrict__ bl, const float* __restrict__ bt,
                                              const float* __restrict__ br, const float* __restrict__ bb,
                                              const float* __restrict__ area,
                                              unsigned long long* __restrict__ mask2) {
    __shared__ float sl[256], st[256], sr[256], sb[256], sa[256];
    int t = threadIdx.x;
    int ic = blockIdx.x >> 4;
    int jc = blockIdx.x & 15;
    int i = ic * 256 + t;
    int j0 = jc * 256;
    sl[t] = bl[j0 + t]; st[t] = bt[j0 + t]; sr[t] = br[j0 + t];
    sb[t] = bb[j0 + t]; sa[t] = area[j0 + t];
    __syncthreads();
    float li = bl[i], ti = bt[i], ri = br[i], bi = bb[i], ai = area[i];
#pragma unroll
    for (int w = 0; w < 4; ++w) {
        unsigned long long m = 0;
        for (int k2 = 0; k2 < 64; ++k2) {
            int j = w * 64 + k2;
            float iw = fminf(ri, sr[j]) - fmaxf(li, sl[j]); iw = fmaxf(iw, 0.f);
            float ih = fminf(bi, sb[j]) - fmaxf(ti, st[j]); ih = fmaxf(ih, 0.f);
            float inter = iw * ih;
            float uni = ai + sa[j] - inter + 1e-10f;
            if (inter / uni >= 0.2f) m |= (1ull << k2);
        }
        mask2[(size_t)(jc * 4 + w) * 4096 + i] = m;
    }
}

// ---------- K7: sequential greedy scan, 1 wave, full-stream pipelined loads ----------
// mask2 layout: word w of row i at mask2[w*4096 + i]  (lane w's stream contiguous in i)
__global__ __launch_bounds__(64) void k_nms(const unsigned long long* __restrict__ mask2,
                                            const float* __restrict__ topv,
                                            const float* __restrict__ area,
                                            unsigned long long* __restrict__ keptW) {
    int lane = threadIdx.x;
    unsigned long long alive = 0, areaok = 0, kept = 0;
    // coalesced init via ballot: iteration k builds word k (bit = lane)
    for (int k = 0; k < 64; ++k) {
        float tv = topv[(size_t)k * 64 + lane];
        float ar = area[(size_t)k * 64 + lane];
        unsigned long long b1 = __ballot(tv != -INFINITY);
        unsigned long long b2 = __ballot(ar >= 4.0f);
        if (lane == k) { alive = b1; areaok = b2; }
    }
    const ulonglong2* mp = (const ulonglong2*)(mask2 + (size_t)lane * 4096);
    unsigned long long cw = 0, caw = 0;
    unsigned long long rA[8], rB[8];

#define LOADB(dst, ib)                                                  \
    {                                                                   \
        _Pragma("unroll") for (int q = 0; q < 4; ++q) {                 \
            ulonglong2 v = mp[(ib) * 4 + q];                            \
            dst[2 * q] = v.x; dst[2 * q + 1] = v.y;                     \
        }                                                               \
    }

#define PROCB(r, ib)                                                    \
    {                                                                   \
        int base = (ib) * 8;                                            \
        _Pragma("unroll") for (int k = 0; k < 8; ++k) {                 \
            int i = base + k;                                           \
            int w = i >> 6;                                             \
            int b = i & 63;                                             \
            if (b == 0) { cw = __shfl(alive, w); caw = __shfl(areaok, w); } \
            unsigned long long bit = 1ull << b;                         \
            if (cw & bit) {                                             \
                if (lane == w) alive &= ~bit;                           \
                cw &= ~bit;                                             \
                unsigned c = __popcll(r[k] & alive);                    \
                unsigned tot = wave_sum64(c);                           \
                if (tot >= 10u && (caw & bit)) {                        \
                    alive &= ~r[k];                                     \
                    unsigned long long mw = __shfl(r[k], w);            \
                    cw &= ~mw;                                          \
                    if (lane == w) kept |= bit;                         \
                }                                                       \
            }                                                           \
        }                                                               \
    }

    LOADB(rA, 0);
    for (int ib = 0; ib < 512; ib += 2) {
        LOADB(rB, ib + 1);
        PROCB(rA, ib);
        if (ib + 2 < 512) LOADB(rA, ib + 2);
        PROCB(rB, ib + 1);
    }
    keptW[lane] = kept;
#undef LOADB
#undef PROCB
}

// ---------- K8: epilogue ----------
__global__ __launch_bounds__(256) void k_out(const unsigned long long* __restrict__ keptW,
                                             const float* __restrict__ topv,
                                             const float* __restrict__ bl, const float* __restrict__ bt,
                                             const float* __restrict__ br, const float* __restrict__ bb,
                                             const int* __restrict__ clsk,
                                             const float* __restrict__ padding,
                                             const float* __restrict__ ratio,
                                             const int* __restrict__ piw, const int* __restrict__ pih,
                                             float* __restrict__ out) {
    int i = blockIdx.x * 256 + threadIdx.x;
    if (i >= KSEL) return;
    bool kept = (keptW[i >> 6] >> (i & 63)) & 1ull;
    float tv = topv[i];
    bool keep = kept && (tv >= 0.5f);
    float p0 = padding[0], p1 = padding[1];
    float invr = 1.0f / ratio[0];
    float W_ = (float)piw[0], H_ = (float)pih[0];
    float x1 = fmaxf((bl[i] - p0) * invr, 0.f);
    float y1 = fmaxf((bt[i] - p1) * invr, 0.f);
    float x2 = fminf((br[i] - p0) * invr, W_);
    float y2 = fminf((bb[i] - p1) * invr, H_);
    keep = keep && (x1 < W_) && (y1 < H_);
    float* o = out + (size_t)i * 7;
    if (keep) {
        o[0] = 1.0f; o[1] = tv; o[2] = x1; o[3] = y1; o[4] = x2; o[5] = y2;
        o[6] = (float)clsk[i];
    } else {
        o[0] = 0.f; o[1] = 0.f; o[2] = 0.f; o[3] = 0.f; o[4] = 0.f; o[5] = 0.f; o[6] = 0.f;
    }
}

extern "C" void kernel_launch(void* const* d_in, const int* in_sizes, int n_in,
                              void* d_out, int out_size, void* d_ws, size_t ws_size,
                              hipStream_t stream) {
    const float* x       = (const float*)d_in[0];
    const float* sm      = (const float*)d_in[1];
    const float* padding = (const float*)d_in[2];
    const float* ratio   = (const float*)d_in[3];
    const int*   piw     = (const int*)d_in[4];
    const int*   pih     = (const int*)d_in[5];
    float* out = (float*)d_out;
    char* ws = (char*)d_ws;

    // workspace layout (bytes)
    float* score               = (float*)(ws + 0);                 // 409600
    int*   clsidx              = (int*)(ws + 409600);              // 409600
    unsigned* hist             = (unsigned*)(ws + 819200);         // 262144
    unsigned* meta             = (unsigned*)(ws + 1081344);        // 512 (meta[0]=counter, meta[1]=p16)
    unsigned long long* cand   = (unsigned long long*)(ws + 1081856); // CAP*8 = 131072
    float* topv                = (float*)(ws + 1212928);           // 16384
    float* bl                  = (float*)(ws + 1229312);
    float* bt                  = (float*)(ws + 1245696);
    float* br                  = (float*)(ws + 1262080);
    float* bb                  = (float*)(ws + 1278464);
    float* area                = (float*)(ws + 1294848);
    int*   clsk                = (int*)(ws + 1311232);
    unsigned long long* keptW  = (unsigned long long*)(ws + 1327616); // 512
    unsigned long long* mask2  = (unsigned long long*)(ws + 1328128); // 2097152

    hipMemsetAsync(hist, 0, 262144 + 512, stream);  // hist + meta

    k_score  <<<400, 256, 0, stream>>>(x, sm, score, clsidx, hist);
    k_findp  <<<1, 1024, 0, stream>>>(hist, meta);
    k_collect<<<400, 256, 0, stream>>>(score, meta, cand);
    k_rank   <<<CAP / 256, 256, 0, stream>>>(cand, meta, x, score, clsidx,
                                             topv, bl, bt, br, bb, area, clsk);
    k_mask   <<<256, 256, 0, stream>>>(bl, bt, br, bb, area, mask2);
    k_nms    <<<1, 64, 0, stream>>>(mask2, topv, area, keptW);
    k_out    <<<16, 256, 0, stream>>>(keptW, topv, bl, bt, br, bb, clsk,
                                      padding, ratio, piw, pih, out);
}

// Round 3
// 1234.862 us; speedup vs baseline: 1.6947x; 1.0251x over previous
//
#include <hip/hip_runtime.h>
#include <hip/hip_bf16.h>
#include <math.h>

#define HW 102400        // 320*320
#define KSEL 4096
#define CAP 16384

// ---------- helpers ----------
__device__ inline unsigned fkey(float f) {
    unsigned u = __float_as_uint(f);
    return (u & 0x80000000u) ? ~u : (u | 0x80000000u);
}

// wave64 sum reduction via DPP (row_shr 1/2/4/8, row_bcast 15/31), result broadcast
__device__ inline unsigned wave_sum64(unsigned x) {
    x += (unsigned)__builtin_amdgcn_update_dpp(0, (int)x, 0x111, 0xf, 0xf, false);
    x += (unsigned)__builtin_amdgcn_update_dpp(0, (int)x, 0x112, 0xf, 0xf, false);
    x += (unsigned)__builtin_amdgcn_update_dpp(0, (int)x, 0x114, 0xf, 0xf, false);
    x += (unsigned)__builtin_amdgcn_update_dpp(0, (int)x, 0x118, 0xf, 0xf, false);
    x += (unsigned)__builtin_amdgcn_update_dpp(0, (int)x, 0x142, 0xa, 0xf, false);
    x += (unsigned)__builtin_amdgcn_update_dpp(0, (int)x, 0x143, 0xc, 0xf, false);
    return (unsigned)__shfl((int)x, 63);
}

__device__ inline void fma16(float xv, const float* __restrict__ srow, float* acc) {
    const float4* s4 = reinterpret_cast<const float4*>(srow);
#pragma unroll
    for (int q = 0; q < 4; ++q) {
        float4 w = s4[q];
        acc[4 * q + 0] = fmaf(xv, w.x, acc[4 * q + 0]);
        acc[4 * q + 1] = fmaf(xv, w.y, acc[4 * q + 1]);
        acc[4 * q + 2] = fmaf(xv, w.z, acc[4 * q + 2]);
        acc[4 * q + 3] = fmaf(xv, w.w, acc[4 * q + 3]);
    }
}

// ---------- K1: score + class argmax (+ fused histogram), deep-ILP loads ----------
// Arithmetic order per pixel is IDENTICAL to the sequential c=0..255 fmaf chain
// (absmax 0.0 vs numpy in prior rounds) — only load scheduling changed.
__global__ __launch_bounds__(256) void k_score(const float* __restrict__ x,
                                               const float* __restrict__ sm,
                                               float* __restrict__ score,
                                               int* __restrict__ clsidx,
                                               unsigned* __restrict__ hist) {
    __shared__ float smt[256][16];   // smt[c][k] = sm[k*256+c]
    int t = threadIdx.x;
    for (int i = t; i < 4096; i += 256) {
        int k = i >> 8, c = i & 255;
        smt[c][k] = sm[k * 256 + c];
    }
    __syncthreads();
    int n = blockIdx.x * 256 + t;
    float acc[16];
#pragma unroll
    for (int k = 0; k < 16; ++k) acc[k] = 0.f;
    const float* xp = x + (size_t)5 * HW + n;

    float va[8], vb[8];
#pragma unroll
    for (int u = 0; u < 8; ++u) va[u] = xp[(size_t)u * HW];
    for (int c0 = 0; c0 < 256; c0 += 16) {
#pragma unroll
        for (int u = 0; u < 8; ++u) vb[u] = xp[(size_t)(c0 + 8 + u) * HW];
#pragma unroll
        for (int u = 0; u < 8; ++u) fma16(va[u], smt[c0 + u], acc);
        if (c0 + 16 < 256) {
#pragma unroll
            for (int u = 0; u < 8; ++u) va[u] = xp[(size_t)(c0 + 16 + u) * HW];
        }
#pragma unroll
        for (int u = 0; u < 8; ++u) fma16(vb[u], smt[c0 + 8 + u], acc);
    }

    float mv = acc[0]; int mi = 0;
#pragma unroll
    for (int k = 1; k < 16; ++k) { if (acc[k] > mv) { mv = acc[k]; mi = k; } }
    float x0 = x[n];
    float sig = 1.0f / (1.0f + expf(-x0));
    float sc = (sig > 0.5f) ? sig * mv : -INFINITY;
    score[n] = sc;
    clsidx[n] = mi;
    atomicAdd(&hist[fkey(sc) >> 16], 1u);
}

// ---------- K3: find 16-bit prefix p16 such that count(key>>16 >= p16) >= K ----------
__global__ __launch_bounds__(1024) void k_findp(const unsigned* __restrict__ hist,
                                                unsigned* __restrict__ meta) {
    __shared__ unsigned part[1024];
    __shared__ unsigned sgrp, s_after;
    __shared__ unsigned bins[64];
    int t = threadIdx.x;
    if (t == 0) { sgrp = 0; s_after = 0; }
    unsigned s = 0;
    const unsigned* hp = hist + t * 64;
    for (int i = 0; i < 64; ++i) s += hp[i];
    part[t] = s;
    __syncthreads();
    for (int off = 1; off < 1024; off <<= 1) {
        unsigned v = (t + off < 1024) ? part[t + off] : 0u;
        __syncthreads();
        part[t] += v;
        __syncthreads();
    }
    if (part[t] >= KSEL && (t == 1023 || part[t + 1] < KSEL)) {
        sgrp = (unsigned)t;
        s_after = (t == 1023) ? 0u : part[t + 1];
    }
    __syncthreads();
    unsigned g = sgrp, SA = s_after;
    if (t < 64) bins[t] = hist[g * 64 + t];
    __syncthreads();
    if (t == 0) {
        unsigned acc = SA, p = g * 64;
        for (int b = 63; b >= 0; --b) {
            acc += bins[b];
            if (acc >= KSEL) { p = g * 64 + (unsigned)b; break; }
        }
        meta[1] = p;
    }
}

// ---------- K4: collect candidates with key>>16 >= p16 ----------
__global__ void k_collect(const float* __restrict__ score,
                          unsigned* __restrict__ meta,
                          unsigned long long* __restrict__ cand) {
    int n = blockIdx.x * 256 + threadIdx.x;
    unsigned key = fkey(score[n]);
    if ((key >> 16) >= meta[1]) {
        unsigned pos = atomicAdd(&meta[0], 1u);
        if (pos < CAP)
            cand[pos] = ((unsigned long long)key << 32) | (unsigned)(~(unsigned)n);
    }
}

// ---------- K5: rank candidates (exact top-k ordering) + gather ----------
__global__ __launch_bounds__(256) void k_rank(const unsigned long long* __restrict__ cand,
                                              const unsigned* __restrict__ meta,
                                              const float* __restrict__ x,
                                              const float* __restrict__ score,
                                              const int* __restrict__ clsidx,
                                              float* __restrict__ topv,
                                              float* __restrict__ bl, float* __restrict__ bt,
                                              float* __restrict__ br, float* __restrict__ bb,
                                              float* __restrict__ area, int* __restrict__ clsk) {
    __shared__ unsigned long long tile[1024];
    int C = (int)meta[0]; if (C > CAP) C = CAP;
    int j = blockIdx.x * 256 + threadIdx.x;
    unsigned long long kj = (j < C) ? cand[j] : 0ull;
    unsigned rank = 0;
    for (int tb = 0; tb < C; tb += 1024) {
        int cnt = min(1024, C - tb);
        __syncthreads();
        for (int u = threadIdx.x; u < cnt; u += 256) tile[u] = cand[tb + u];
        __syncthreads();
        if (j < C)
            for (int u = 0; u < cnt; ++u) rank += (tile[u] > kj) ? 1u : 0u;
    }
    if (j < C && rank < KSEL) {
        unsigned n = ~(unsigned)(kj & 0xFFFFFFFFull);
        float l  = x[(size_t)1 * HW + n];
        float tt = x[(size_t)2 * HW + n];
        float r  = x[(size_t)3 * HW + n];
        float b  = x[(size_t)4 * HW + n];
        topv[rank] = score[n];
        bl[rank] = l; bt[rank] = tt; br[rank] = r; bb[rank] = b;
        area[rank] = (r - l) * (b - tt);
        clsk[rank] = clsidx[n];
    }
}

// ---------- K6: pairwise IoU >= 0.2 bitmask, ROW-MAJOR mask[i][w] ----------
// grid: 256 blocks = 16 i-chunks x 16 j-chunks; LDS-staged j-slice, broadcast reads.
__global__ __launch_bounds__(256) void k_mask(const float* __restrict__ bl, const float* __restrict__ bt,
                                              const float* __restrict__ br, const float* __restrict__ bb,
                                              const float* __restrict__ area,
                                              unsigned long long* __restrict__ mask) {
    __shared__ float sl[256], st[256], sr[256], sb[256], sa[256];
    int t = threadIdx.x;
    int ic = blockIdx.x >> 4;
    int jc = blockIdx.x & 15;
    int i = ic * 256 + t;
    int j0 = jc * 256;
    sl[t] = bl[j0 + t]; st[t] = bt[j0 + t]; sr[t] = br[j0 + t];
    sb[t] = bb[j0 + t]; sa[t] = area[j0 + t];
    __syncthreads();
    float li = bl[i], ti = bt[i], ri = br[i], bi = bb[i], ai = area[i];
#pragma unroll
    for (int w = 0; w < 4; ++w) {
        unsigned long long m = 0;
        for (int k2 = 0; k2 < 64; ++k2) {
            int j = w * 64 + k2;
            float iw = fminf(ri, sr[j]) - fmaxf(li, sl[j]); iw = fmaxf(iw, 0.f);
            float ih = fminf(bi, sb[j]) - fmaxf(ti, st[j]); ih = fmaxf(ih, 0.f);
            float inter = iw * ih;
            float uni = ai + sa[j] - inter + 1e-10f;
            if (inter / uni >= 0.2f) m |= (1ull << k2);
        }
        mask[(size_t)i * 64 + (jc * 4 + w)] = m;
    }
}

// ---------- K7: sequential greedy scan, 1 wave, pipelined ROW loads ----------
// mask row-major: row i = mask[i*64 .. i*64+63]; lane w holds word w.
// One wave-load per row = 512 B contiguous (8 cache lines).
__global__ __launch_bounds__(64) void k_nms(const unsigned long long* __restrict__ mask,
                                            const float* __restrict__ topv,
                                            const float* __restrict__ area,
                                            unsigned long long* __restrict__ keptW) {
    int lane = threadIdx.x;
    unsigned long long alive = 0, areaok = 0, kept = 0;
    // coalesced init via ballot: iteration k builds word k (bit = lane)
    for (int k = 0; k < 64; ++k) {
        float tv = topv[(size_t)k * 64 + lane];
        float ar = area[(size_t)k * 64 + lane];
        unsigned long long b1 = __ballot(tv != -INFINITY);
        unsigned long long b2 = __ballot(ar >= 4.0f);
        if (lane == k) { alive = b1; areaok = b2; }
    }
    const unsigned long long* mrow = mask + lane;   // mask[i*64 + lane]
    unsigned long long cw = 0, caw = 0;
    unsigned long long rA[8], rB[8];

#define LOADB(dst, ib)                                                  \
    {                                                                   \
        _Pragma("unroll") for (int k = 0; k < 8; ++k)                   \
            dst[k] = mrow[(size_t)((ib) * 8 + k) * 64];                 \
    }

#define PROCB(r, ib)                                                    \
    {                                                                   \
        int base = (ib) * 8;                                            \
        _Pragma("unroll") for (int k = 0; k < 8; ++k) {                 \
            int i = base + k;                                           \
            int w = i >> 6;                                             \
            int b = i & 63;                                             \
            if (b == 0) { cw = __shfl(alive, w); caw = __shfl(areaok, w); } \
            unsigned long long bit = 1ull << b;                         \
            if (cw & bit) {                                             \
                if (lane == w) alive &= ~bit;                           \
                cw &= ~bit;                                             \
                unsigned c = __popcll(r[k] & alive);                    \
                unsigned tot = wave_sum64(c);                           \
                if (tot >= 10u && (caw & bit)) {                        \
                    alive &= ~r[k];                                     \
                    unsigned long long mw = __shfl(r[k], w);            \
                    cw &= ~mw;                                          \
                    if (lane == w) kept |= bit;                         \
                }                                                       \
            }                                                           \
        }                                                               \
    }

    LOADB(rA, 0);
    for (int ib = 0; ib < 512; ib += 2) {
        LOADB(rB, ib + 1);
        PROCB(rA, ib);
        if (ib + 2 < 512) LOADB(rA, ib + 2);
        PROCB(rB, ib + 1);
    }
    keptW[lane] = kept;
#undef LOADB
#undef PROCB
}

// ---------- K8: epilogue ----------
__global__ __launch_bounds__(256) void k_out(const unsigned long long* __restrict__ keptW,
                                             const float* __restrict__ topv,
                                             const float* __restrict__ bl, const float* __restrict__ bt,
                                             const float* __restrict__ br, const float* __restrict__ bb,
                                             const int* __restrict__ clsk,
                                             const float* __restrict__ padding,
                                             const float* __restrict__ ratio,
                                             const int* __restrict__ piw, const int* __restrict__ pih,
                                             float* __restrict__ out) {
    int i = blockIdx.x * 256 + threadIdx.x;
    if (i >= KSEL) return;
    bool kept = (keptW[i >> 6] >> (i & 63)) & 1ull;
    float tv = topv[i];
    bool keep = kept && (tv >= 0.5f);
    float p0 = padding[0], p1 = padding[1];
    float invr = 1.0f / ratio[0];
    float W_ = (float)piw[0], H_ = (float)pih[0];
    float x1 = fmaxf((bl[i] - p0) * invr, 0.f);
    float y1 = fmaxf((bt[i] - p1) * invr, 0.f);
    float x2 = fminf((br[i] - p0) * invr, W_);
    float y2 = fminf((bb[i] - p1) * invr, H_);
    keep = keep && (x1 < W_) && (y1 < H_);
    float* o = out + (size_t)i * 7;
    if (keep) {
        o[0] = 1.0f; o[1] = tv; o[2] = x1; o[3] = y1; o[4] = x2; o[5] = y2;
        o[6] = (float)clsk[i];
    } else {
        o[0] = 0.f; o[1] = 0.f; o[2] = 0.f; o[3] = 0.f; o[4] = 0.f; o[5] = 0.f; o[6] = 0.f;
    }
}

extern "C" void kernel_launch(void* const* d_in, const int* in_sizes, int n_in,
                              void* d_out, int out_size, void* d_ws, size_t ws_size,
                              hipStream_t stream) {
    const float* x       = (const float*)d_in[0];
    const float* sm      = (const float*)d_in[1];
    const float* padding = (const float*)d_in[2];
    const float* ratio   = (const float*)d_in[3];
    const int*   piw     = (const int*)d_in[4];
    const int*   pih     = (const int*)d_in[5];
    float* out = (float*)d_out;
    char* ws = (char*)d_ws;

    // workspace layout (bytes)
    float* score               = (float*)(ws + 0);                 // 409600
    int*   clsidx              = (int*)(ws + 409600);              // 409600
    unsigned* hist             = (unsigned*)(ws + 819200);         // 262144
    unsigned* meta             = (unsigned*)(ws + 1081344);        // 512 (meta[0]=counter, meta[1]=p16)
    unsigned long long* cand   = (unsigned long long*)(ws + 1081856); // CAP*8 = 131072
    float* topv                = (float*)(ws + 1212928);           // 16384
    float* bl                  = (float*)(ws + 1229312);
    float* bt                  = (float*)(ws + 1245696);
    float* br                  = (float*)(ws + 1262080);
    float* bb                  = (float*)(ws + 1278464);
    float* area                = (float*)(ws + 1294848);
    int*   clsk                = (int*)(ws + 1311232);
    unsigned long long* keptW  = (unsigned long long*)(ws + 1327616); // 512
    unsigned long long* mask   = (unsigned long long*)(ws + 1328128); // 2097152

    hipMemsetAsync(hist, 0, 262144 + 512, stream);  // hist + meta

    k_score  <<<400, 256, 0, stream>>>(x, sm, score, clsidx, hist);
    k_findp  <<<1, 1024, 0, stream>>>(hist, meta);
    k_collect<<<400, 256, 0, stream>>>(score, meta, cand);
    k_rank   <<<CAP / 256, 256, 0, stream>>>(cand, meta, x, score, clsidx,
                                             topv, bl, bt, br, bb, area, clsk);
    k_mask   <<<256, 256, 0, stream>>>(bl, bt, br, bb, area, mask);
    k_nms    <<<1, 64, 0, stream>>>(mask, topv, area, keptW);
    k_out    <<<16, 256, 0, stream>>>(keptW, topv, bl, bt, br, bb, clsk,
                                      padding, ratio, piw, pih, out);
}

// Round 4
// 1203.302 us; speedup vs baseline: 1.7391x; 1.0262x over previous
//
#include <hip/hip_runtime.h>
#include <hip/hip_bf16.h>
#include <math.h>

#define HW 102400        // 320*320
#define KSEL 4096
#define CAP 16384

// ---------- helpers ----------
__device__ inline unsigned fkey(float f) {
    unsigned u = __float_as_uint(f);
    return (u & 0x80000000u) ? ~u : (u | 0x80000000u);
}

// wave64 sum via DPP (row_shr 1/2/4/8 + row_bcast 15/31); result valid in lane 63,
// returned through readlane -> SGPR (wave-uniform, enables scalar branch).
__device__ inline unsigned wave_sum64_s(unsigned x) {
    x += (unsigned)__builtin_amdgcn_update_dpp(0, (int)x, 0x111, 0xf, 0xf, false);
    x += (unsigned)__builtin_amdgcn_update_dpp(0, (int)x, 0x112, 0xf, 0xf, false);
    x += (unsigned)__builtin_amdgcn_update_dpp(0, (int)x, 0x114, 0xf, 0xf, false);
    x += (unsigned)__builtin_amdgcn_update_dpp(0, (int)x, 0x118, 0xf, 0xf, false);
    x += (unsigned)__builtin_amdgcn_update_dpp(0, (int)x, 0x142, 0xa, 0xf, false);
    x += (unsigned)__builtin_amdgcn_update_dpp(0, (int)x, 0x143, 0xc, 0xf, false);
    return (unsigned)__builtin_amdgcn_readlane((int)x, 63);
}

// ---------- K1: score + class argmax (+ fused histogram) ----------
// thread = (4-pixel quad, 4-class group). float4 x loads, b128 broadcast weights.
// Per-class accumulation is the exact sequential c=0..255 fmaf chain (bit-stable
// vs prior rounds' absmax 0.0). Argmax merged group-ascending, strictly-greater
// => identical first-max-index semantics.
__global__ __launch_bounds__(128) void k_score(const float* __restrict__ x,
                                               const float* __restrict__ sm,
                                               float* __restrict__ score,
                                               int* __restrict__ clsidx,
                                               unsigned* __restrict__ hist) {
    __shared__ float swt[256][16];     // swt[c][k] = sm[k*256+c]
    __shared__ float lred_v[128][4];
    __shared__ int   lred_i[128][4];
    int t = threadIdx.x;
    for (int i = t; i < 4096; i += 128) {
        int k = i >> 8, c = i & 255;
        swt[c][k] = sm[i];
    }
    __syncthreads();

    int q  = t & 31;          // quad within block
    int g  = t >> 5;          // class group (4 classes each)
    size_t qg = (size_t)blockIdx.x * 32 + q;   // global quad id (pixels 4qg..4qg+3)
    const float4* xb = (const float4*)x;       // x as float4; channel c at (5+c)*25600

    float acc[4][4];          // [cls within group][pixel in quad]
#pragma unroll
    for (int k = 0; k < 4; ++k)
#pragma unroll
        for (int s = 0; s < 4; ++s) acc[k][s] = 0.f;

    float4 va[16], vb[16];
#pragma unroll
    for (int u = 0; u < 16; ++u) va[u] = xb[(size_t)(5 + u) * 25600 + qg];

#define FMABATCH(vv, cbase)                                               \
    _Pragma("unroll") for (int u = 0; u < 16; ++u) {                      \
        const float4 wv = *(const float4*)&swt[(cbase) + u][g * 4];       \
        float4 xv = vv[u];                                                \
        acc[0][0] = fmaf(xv.x, wv.x, acc[0][0]);                          \
        acc[0][1] = fmaf(xv.y, wv.x, acc[0][1]);                          \
        acc[0][2] = fmaf(xv.z, wv.x, acc[0][2]);                          \
        acc[0][3] = fmaf(xv.w, wv.x, acc[0][3]);                          \
        acc[1][0] = fmaf(xv.x, wv.y, acc[1][0]);                          \
        acc[1][1] = fmaf(xv.y, wv.y, acc[1][1]);                          \
        acc[1][2] = fmaf(xv.z, wv.y, acc[1][2]);                          \
        acc[1][3] = fmaf(xv.w, wv.y, acc[1][3]);                          \
        acc[2][0] = fmaf(xv.x, wv.z, acc[2][0]);                          \
        acc[2][1] = fmaf(xv.y, wv.z, acc[2][1]);                          \
        acc[2][2] = fmaf(xv.z, wv.z, acc[2][2]);                          \
        acc[2][3] = fmaf(xv.w, wv.z, acc[2][3]);                          \
        acc[3][0] = fmaf(xv.x, wv.w, acc[3][0]);                          \
        acc[3][1] = fmaf(xv.y, wv.w, acc[3][1]);                          \
        acc[3][2] = fmaf(xv.z, wv.w, acc[3][2]);                          \
        acc[3][3] = fmaf(xv.w, wv.w, acc[3][3]);                          \
    }

    for (int c0 = 0; c0 < 256; c0 += 32) {
#pragma unroll
        for (int u = 0; u < 16; ++u) vb[u] = xb[(size_t)(5 + c0 + 16 + u) * 25600 + qg];
        FMABATCH(va, c0);
        if (c0 + 32 < 256) {
#pragma unroll
            for (int u = 0; u < 16; ++u) va[u] = xb[(size_t)(5 + c0 + 32 + u) * 25600 + qg];
        }
        FMABATCH(vb, c0 + 16);
    }
#undef FMABATCH

    // per-group argmax (strictly greater, ascending class)
#pragma unroll
    for (int s = 0; s < 4; ++s) {
        float mv = acc[0][s]; int mi = 4 * g;
#pragma unroll
        for (int k = 1; k < 4; ++k)
            if (acc[k][s] > mv) { mv = acc[k][s]; mi = 4 * g + k; }
        lred_v[q * 4 + s][g] = mv;
        lred_i[q * 4 + s][g] = mi;
    }
    __syncthreads();

    // final merge: thread t owns pixel block*128 + t
    {
        int n = blockIdx.x * 128 + t;
        float mv = lred_v[t][0]; int mi = lred_i[t][0];
#pragma unroll
        for (int g2 = 1; g2 < 4; ++g2) {
            float v = lred_v[t][g2];
            if (v > mv) { mv = v; mi = lred_i[t][g2]; }
        }
        float x0 = x[n];
        float sig = 1.0f / (1.0f + expf(-x0));
        float sc = (sig > 0.5f) ? sig * mv : -INFINITY;
        score[n] = sc;
        clsidx[n] = mi;
        atomicAdd(&hist[fkey(sc) >> 16], 1u);
    }
}

// ---------- K3: find 16-bit prefix p16 such that count(key>>16 >= p16) >= K ----------
__global__ __launch_bounds__(1024) void k_findp(const unsigned* __restrict__ hist,
                                                unsigned* __restrict__ meta) {
    __shared__ unsigned part[1024];
    __shared__ unsigned sgrp, s_after;
    __shared__ unsigned bins[64];
    int t = threadIdx.x;
    if (t == 0) { sgrp = 0; s_after = 0; }
    unsigned s = 0;
    const unsigned* hp = hist + t * 64;
    for (int i = 0; i < 64; ++i) s += hp[i];
    part[t] = s;
    __syncthreads();
    for (int off = 1; off < 1024; off <<= 1) {
        unsigned v = (t + off < 1024) ? part[t + off] : 0u;
        __syncthreads();
        part[t] += v;
        __syncthreads();
    }
    if (part[t] >= KSEL && (t == 1023 || part[t + 1] < KSEL)) {
        sgrp = (unsigned)t;
        s_after = (t == 1023) ? 0u : part[t + 1];
    }
    __syncthreads();
    unsigned g = sgrp, SA = s_after;
    if (t < 64) bins[t] = hist[g * 64 + t];
    __syncthreads();
    if (t == 0) {
        unsigned acc = SA, p = g * 64;
        for (int b = 63; b >= 0; --b) {
            acc += bins[b];
            if (acc >= KSEL) { p = g * 64 + (unsigned)b; break; }
        }
        meta[1] = p;
    }
}

// ---------- K4: collect candidates with key>>16 >= p16 ----------
__global__ void k_collect(const float* __restrict__ score,
                          unsigned* __restrict__ meta,
                          unsigned long long* __restrict__ cand) {
    int n = blockIdx.x * 256 + threadIdx.x;
    unsigned key = fkey(score[n]);
    if ((key >> 16) >= meta[1]) {
        unsigned pos = atomicAdd(&meta[0], 1u);
        if (pos < CAP)
            cand[pos] = ((unsigned long long)key << 32) | (unsigned)(~(unsigned)n);
    }
}

// ---------- K5: rank candidates (exact top-k ordering) + gather ----------
__global__ __launch_bounds__(256) void k_rank(const unsigned long long* __restrict__ cand,
                                              const unsigned* __restrict__ meta,
                                              const float* __restrict__ x,
                                              const float* __restrict__ score,
                                              const int* __restrict__ clsidx,
                                              float* __restrict__ topv,
                                              float* __restrict__ bl, float* __restrict__ bt,
                                              float* __restrict__ br, float* __restrict__ bb,
                                              float* __restrict__ area, int* __restrict__ clsk) {
    __shared__ unsigned long long tile[1024];
    int C = (int)meta[0]; if (C > CAP) C = CAP;
    int j = blockIdx.x * 256 + threadIdx.x;
    unsigned long long kj = (j < C) ? cand[j] : 0ull;
    unsigned rank = 0;
    for (int tb = 0; tb < C; tb += 1024) {
        int cnt = min(1024, C - tb);
        __syncthreads();
        for (int u = threadIdx.x; u < cnt; u += 256) tile[u] = cand[tb + u];
        __syncthreads();
        if (j < C)
            for (int u = 0; u < cnt; ++u) rank += (tile[u] > kj) ? 1u : 0u;
    }
    if (j < C && rank < KSEL) {
        unsigned n = ~(unsigned)(kj & 0xFFFFFFFFull);
        float l  = x[(size_t)1 * HW + n];
        float tt = x[(size_t)2 * HW + n];
        float r  = x[(size_t)3 * HW + n];
        float b  = x[(size_t)4 * HW + n];
        topv[rank] = score[n];
        bl[rank] = l; bt[rank] = tt; br[rank] = r; bb[rank] = b;
        area[rank] = (r - l) * (b - tt);
        clsk[rank] = clsidx[n];
    }
}

// ---------- K6: pairwise IoU >= 0.2 bitmask, ROW-MAJOR mask[i][w] ----------
__global__ __launch_bounds__(256) void k_mask(const float* __restrict__ bl, const float* __restrict__ bt,
                                              const float* __restrict__ br, const float* __restrict__ bb,
                                              const float* __restrict__ area,
                                              unsigned long long* __restrict__ mask) {
    __shared__ float sl[256], st[256], sr[256], sb[256], sa[256];
    int t = threadIdx.x;
    int ic = blockIdx.x >> 4;
    int jc = blockIdx.x & 15;
    int i = ic * 256 + t;
    int j0 = jc * 256;
    sl[t] = bl[j0 + t]; st[t] = bt[j0 + t]; sr[t] = br[j0 + t];
    sb[t] = bb[j0 + t]; sa[t] = area[j0 + t];
    __syncthreads();
    float li = bl[i], ti = bt[i], ri = br[i], bi = bb[i], ai = area[i];
#pragma unroll
    for (int w = 0; w < 4; ++w) {
        unsigned long long m = 0;
        for (int k2 = 0; k2 < 64; ++k2) {
            int j = w * 64 + k2;
            float iw = fminf(ri, sr[j]) - fmaxf(li, sl[j]); iw = fmaxf(iw, 0.f);
            float ih = fminf(bi, sb[j]) - fmaxf(ti, st[j]); ih = fmaxf(ih, 0.f);
            float inter = iw * ih;
            float uni = ai + sa[j] - inter + 1e-10f;
            if (inter / uni >= 0.2f) m |= (1ull << k2);
        }
        mask[(size_t)i * 64 + (jc * 4 + w)] = m;
    }
}

// ---------- K7: sequential greedy scan, 1 wave, 4-deep (32-row) prefetch ----------
__global__ __launch_bounds__(64) void k_nms(const unsigned long long* __restrict__ mask,
                                            const float* __restrict__ topv,
                                            const float* __restrict__ area,
                                            unsigned long long* __restrict__ keptW) {
    int lane = threadIdx.x;
    unsigned long long alive = 0, areaok = 0, kept = 0;
    for (int k = 0; k < 64; ++k) {
        float tv = topv[(size_t)k * 64 + lane];
        float ar = area[(size_t)k * 64 + lane];
        unsigned long long b1 = __ballot(tv != -INFINITY);
        unsigned long long b2 = __ballot(ar >= 4.0f);
        if (lane == k) { alive = b1; areaok = b2; }
    }
    const unsigned long long* mrow = mask + lane;   // mask[i*64 + lane]
    unsigned long long cw = 0, caw = 0;
    unsigned long long q0[8], q1[8], q2[8], q3[8];

#define LOADB(dst, ib)                                                  \
    {                                                                   \
        _Pragma("unroll") for (int k = 0; k < 8; ++k)                   \
            dst[k] = mrow[(size_t)((ib) * 8 + k) * 64];                 \
    }

#define PROCB(r, ib)                                                    \
    {                                                                   \
        int base = (ib) * 8;                                            \
        _Pragma("unroll") for (int k = 0; k < 8; ++k) {                 \
            int i = base + k;                                           \
            int w = i >> 6;                                             \
            int b = i & 63;                                             \
            if (b == 0) { cw = __shfl(alive, w); caw = __shfl(areaok, w); } \
            unsigned long long bit = 1ull << b;                         \
            if (cw & bit) {                                             \
                if (lane == w) alive &= ~bit;                           \
                cw &= ~bit;                                             \
                unsigned c = __popcll(r[k] & alive);                    \
                unsigned tot = wave_sum64_s(c);                         \
                if (tot >= 10u && (caw & bit)) {                        \
                    alive &= ~r[k];                                     \
                    unsigned long long mw = __shfl(r[k], w);            \
                    cw &= ~mw;                                          \
                    if (lane == w) kept |= bit;                         \
                }                                                       \
            }                                                           \
        }                                                               \
    }

    LOADB(q0, 0); LOADB(q1, 1); LOADB(q2, 2); LOADB(q3, 3);
    for (int ib = 0; ib < 512; ib += 4) {
        PROCB(q0, ib);
        if (ib + 4 < 512) LOADB(q0, ib + 4);
        PROCB(q1, ib + 1);
        if (ib + 5 < 512) LOADB(q1, ib + 5);
        PROCB(q2, ib + 2);
        if (ib + 6 < 512) LOADB(q2, ib + 6);
        PROCB(q3, ib + 3);
        if (ib + 7 < 512) LOADB(q3, ib + 7);
    }
    keptW[lane] = kept;
#undef LOADB
#undef PROCB
}

// ---------- K8: epilogue ----------
__global__ __launch_bounds__(256) void k_out(const unsigned long long* __restrict__ keptW,
                                             const float* __restrict__ topv,
                                             const float* __restrict__ bl, const float* __restrict__ bt,
                                             const float* __restrict__ br, const float* __restrict__ bb,
                                             const int* __restrict__ clsk,
                                             const float* __restrict__ padding,
                                             const float* __restrict__ ratio,
                                             const int* __restrict__ piw, const int* __restrict__ pih,
                                             float* __restrict__ out) {
    int i = blockIdx.x * 256 + threadIdx.x;
    if (i >= KSEL) return;
    bool kept = (keptW[i >> 6] >> (i & 63)) & 1ull;
    float tv = topv[i];
    bool keep = kept && (tv >= 0.5f);
    float p0 = padding[0], p1 = padding[1];
    float invr = 1.0f / ratio[0];
    float W_ = (float)piw[0], H_ = (float)pih[0];
    float x1 = fmaxf((bl[i] - p0) * invr, 0.f);
    float y1 = fmaxf((bt[i] - p1) * invr, 0.f);
    float x2 = fminf((br[i] - p0) * invr, W_);
    float y2 = fminf((bb[i] - p1) * invr, H_);
    keep = keep && (x1 < W_) && (y1 < H_);
    float* o = out + (size_t)i * 7;
    if (keep) {
        o[0] = 1.0f; o[1] = tv; o[2] = x1; o[3] = y1; o[4] = x2; o[5] = y2;
        o[6] = (float)clsk[i];
    } else {
        o[0] = 0.f; o[1] = 0.f; o[2] = 0.f; o[3] = 0.f; o[4] = 0.f; o[5] = 0.f; o[6] = 0.f;
    }
}

extern "C" void kernel_launch(void* const* d_in, const int* in_sizes, int n_in,
                              void* d_out, int out_size, void* d_ws, size_t ws_size,
                              hipStream_t stream) {
    const float* x       = (const float*)d_in[0];
    const float* sm      = (const float*)d_in[1];
    const float* padding = (const float*)d_in[2];
    const float* ratio   = (const float*)d_in[3];
    const int*   piw     = (const int*)d_in[4];
    const int*   pih     = (const int*)d_in[5];
    float* out = (float*)d_out;
    char* ws = (char*)d_ws;

    // workspace layout (bytes)
    float* score               = (float*)(ws + 0);                 // 409600
    int*   clsidx              = (int*)(ws + 409600);              // 409600
    unsigned* hist             = (unsigned*)(ws + 819200);         // 262144
    unsigned* meta             = (unsigned*)(ws + 1081344);        // 512 (meta[0]=counter, meta[1]=p16)
    unsigned long long* cand   = (unsigned long long*)(ws + 1081856); // CAP*8 = 131072
    float* topv                = (float*)(ws + 1212928);           // 16384
    float* bl                  = (float*)(ws + 1229312);
    float* bt                  = (float*)(ws + 1245696);
    float* br                  = (float*)(ws + 1262080);
    float* bb                  = (float*)(ws + 1278464);
    float* area                = (float*)(ws + 1294848);
    int*   clsk                = (int*)(ws + 1311232);
    unsigned long long* keptW  = (unsigned long long*)(ws + 1327616); // 512
    unsigned long long* mask   = (unsigned long long*)(ws + 1328128); // 2097152

    hipMemsetAsync(hist, 0, 262144 + 512, stream);  // hist + meta

    k_score  <<<800, 128, 0, stream>>>(x, sm, score, clsidx, hist);
    k_findp  <<<1, 1024, 0, stream>>>(hist, meta);
    k_collect<<<400, 256, 0, stream>>>(score, meta, cand);
    k_rank   <<<CAP / 256, 256, 0, stream>>>(cand, meta, x, score, clsidx,
                                             topv, bl, bt, br, bb, area, clsk);
    k_mask   <<<256, 256, 0, stream>>>(bl, bt, br, bb, area, mask);
    k_nms    <<<1, 64, 0, stream>>>(mask, topv, area, keptW);
    k_out    <<<16, 256, 0, stream>>>(keptW, topv, bl, bt, br, bb, clsk,
                                      padding, ratio, piw, pih, out);
}